// Round 6
// baseline (279.264 us; speedup 1.0000x reference)
//
#include <hip/hip_runtime.h>
#include <hip/hip_bf16.h>
#include <float.h>
#include <math.h>

#define N 4096
#define DIN 64

typedef signed char i8_t;
typedef signed char i8x4 __attribute__((ext_vector_type(4)));
typedef int i32x4 __attribute__((ext_vector_type(4)));
typedef float f32x4 __attribute__((ext_vector_type(4)));

// ---------- async global->LDS, 16B per lane ----------
__device__ __forceinline__ void gload16(const void* g, void* l) {
    __builtin_amdgcn_global_load_lds((const __attribute__((address_space(1))) void*)g,
                                     (__attribute__((address_space(3))) void*)l,
                                     16, 0, 0);
}

__device__ __forceinline__ float block_reduce_sum(float s) {
    __shared__ float red[4];
    #pragma unroll
    for (int off = 32; off; off >>= 1) s += __shfl_down(s, off);
    if ((threadIdx.x & 63) == 0) red[threadIdx.x >> 6] = s;
    __syncthreads();
    return red[0] + red[1] + red[2] + red[3];
}

// two sums at once (avoids back-to-back shared-buffer races of calling twice)
__device__ __forceinline__ float2 block_reduce_sum2(float a, float b) {
    __shared__ float reda[4], redb[4];
    #pragma unroll
    for (int off = 32; off; off >>= 1) { a += __shfl_down(a, off); b += __shfl_down(b, off); }
    if ((threadIdx.x & 63) == 0) { reda[threadIdx.x >> 6] = a; redb[threadIdx.x >> 6] = b; }
    __syncthreads();
    float2 r;
    r.x = reda[0] + reda[1] + reda[2] + reda[3];
    r.y = redb[0] + redb[1] + redb[2] + redb[3];
    return r;
}

// ---------- top-4 insertion with tie -> lower index ----------
__device__ __forceinline__ bool better(float v1, int j1, float v2, int j2) {
    return v1 > v2 || (v1 == v2 && j1 < j2);
}
__device__ __forceinline__ void ins4(float v, int j, float bv[4], int bj[4]) {
    if (!better(v, j, bv[3], bj[3])) return;
    bv[3] = v; bj[3] = j;
    if (better(bv[3], bj[3], bv[2], bj[2])) {
        float tv = bv[2]; int tj = bj[2]; bv[2] = bv[3]; bj[2] = bj[3]; bv[3] = tv; bj[3] = tj;
    }
    if (better(bv[2], bj[2], bv[1], bj[1])) {
        float tv = bv[1]; int tj = bj[1]; bv[1] = bv[2]; bj[1] = bj[2]; bv[2] = tv; bj[2] = tj;
    }
    if (better(bv[1], bj[1], bv[0], bj[0])) {
        float tv = bv[0]; int tj = bj[0]; bv[0] = bv[1]; bj[0] = bj[1]; bv[1] = tv; bj[1] = tj;
    }
}

// ---------- K1: rowsums of A -> dinv = 1/sqrt(d) ----------
__global__ __launch_bounds__(256) void k_rowsum_dinv(const float* __restrict__ A,
                                                     float* __restrict__ dinv) {
    int row = blockIdx.x, tid = threadIdx.x;
    const float4* a4 = (const float4*)(A + (size_t)row * N);
    float s = 0.f;
    for (int j = tid; j < N / 4; j += 256) {
        float4 v = a4[j];
        s += v.x + v.y + v.z + v.w;
    }
    float tot = block_reduce_sum(s);
    if (tid == 0) dinv[row] = rsqrtf(tot);
}

// ---------- K2: dmax = max(dinv), single block ----------
__global__ __launch_bounds__(1024) void k_dmax(const float* __restrict__ dinv,
                                               float* __restrict__ dmaxf) {
    int t = threadIdx.x;
    float m = fmaxf(fmaxf(dinv[t], dinv[t + 1024]), fmaxf(dinv[t + 2048], dinv[t + 3072]));
    #pragma unroll
    for (int off = 32; off; off >>= 1) m = fmaxf(m, __shfl_down(m, off));
    __shared__ float red[16];
    if ((t & 63) == 0) red[t >> 6] = m;
    __syncthreads();
    if (t == 0) {
        float mm = red[0];
        #pragma unroll
        for (int i = 1; i < 16; i++) mm = fmaxf(mm, red[i]);
        *dmaxf = mm;
    }
}

// ---------- K3: Sq = i8(S), Tq = i8(S^T); q = rint(S * 127/dmax^2) ----------
__global__ __launch_bounds__(256) void k_make_sqt(const float* __restrict__ A,
                                                  const float* __restrict__ dinv,
                                                  const float* __restrict__ dmaxf,
                                                  i8_t* __restrict__ Sq,
                                                  i8_t* __restrict__ Tq) {
    __shared__ float tile[64][65];
    int tid = threadIdx.x;
    int c4 = tid & 15;   // column group (4 cols)
    int rg = tid >> 4;   // 0..15
    int i0 = blockIdx.y * 64;
    int j0 = blockIdx.x * 64;
    float dmax = *dmaxf;
    float sinv = 127.0f / (dmax * dmax);
    float4 dj = *(const float4*)(dinv + j0 + 4 * c4);
    #pragma unroll
    for (int rr = 0; rr < 4; rr++) {
        int r = rg + 16 * rr;
        int row = i0 + r;
        float di = dinv[row];
        float4 av = *(const float4*)(A + (size_t)row * N + j0 + 4 * c4);
        float s0 = av.x * di * dj.x, s1 = av.y * di * dj.y;
        float s2 = av.z * di * dj.z, s3 = av.w * di * dj.w;
        i8x4 qv;
        qv[0] = (i8_t)(int)fminf(rintf(s0 * sinv), 127.f);
        qv[1] = (i8_t)(int)fminf(rintf(s1 * sinv), 127.f);
        qv[2] = (i8_t)(int)fminf(rintf(s2 * sinv), 127.f);
        qv[3] = (i8_t)(int)fminf(rintf(s3 * sinv), 127.f);
        *(i8x4*)(Sq + (size_t)row * N + j0 + 4 * c4) = qv;
        tile[r][4 * c4 + 0] = s0;
        tile[r][4 * c4 + 1] = s1;
        tile[r][4 * c4 + 2] = s2;
        tile[r][4 * c4 + 3] = s3;
    }
    __syncthreads();
    #pragma unroll
    for (int cc = 0; cc < 4; cc++) {
        int c = rg + 16 * cc;
        int gj = j0 + c;
        i8x4 qv;
        #pragma unroll
        for (int u = 0; u < 4; u++)
            qv[u] = (i8_t)(int)fminf(rintf(tile[4 * c4 + u][c] * sinv), 127.f);
        *(i8x4*)(Tq + (size_t)gj * N + i0 + 4 * c4) = qv;
    }
}

// ---------- K4: colsumQ[k] = sum_j Q[j][k] = rowsum of Tq row k (exact in float) ----------
__global__ __launch_bounds__(256) void k_colsum(const i8_t* __restrict__ Tq,
                                                float* __restrict__ colsumQ) {
    int row = blockIdx.x, tid = threadIdx.x;
    int4 w = ((const int4*)(Tq + (size_t)row * N))[tid];  // 16 bytes
    int s = 0;
    #pragma unroll
    for (int u = 0; u < 4; u++) {
        int wv = (u == 0) ? w.x : (u == 1) ? w.y : (u == 2) ? w.z : w.w;
        s += (int)(i8_t)(wv) + (int)(i8_t)(wv >> 8) + (int)(i8_t)(wv >> 16) + (int)(i8_t)(wv >> 24);
    }
    float tot = block_reduce_sum((float)s);  // exact: |total| <= 127*4096 < 2^24
    if (tid == 0) colsumQ[row] = tot;
}

// ---------- K5: dinv2[i] = rsqrt(t1s2*dot(Q_i, colsumQ) + t0s*rowQ_i + 1) ----------
__global__ __launch_bounds__(256) void k_dinv2row(const i8_t* __restrict__ Sq,
                                                  const float* __restrict__ colsumQ,
                                                  const float* __restrict__ dmaxf,
                                                  const float* __restrict__ theta,
                                                  float* __restrict__ dinv2) {
    int row = blockIdx.x, tid = threadIdx.x;
    int4 w = ((const int4*)(Sq + (size_t)row * N))[tid];
    float dot = 0.f, rq = 0.f;
    #pragma unroll
    for (int u = 0; u < 4; u++) {
        int wv = (u == 0) ? w.x : (u == 1) ? w.y : (u == 2) ? w.z : w.w;
        float4 cv = ((const float4*)colsumQ)[tid * 4 + u];
        float q0 = (float)(i8_t)(wv), q1 = (float)(i8_t)(wv >> 8);
        float q2 = (float)(i8_t)(wv >> 16), q3 = (float)(i8_t)(wv >> 24);
        dot += q0 * cv.x + q1 * cv.y + q2 * cv.z + q3 * cv.w;
        rq += q0 + q1 + q2 + q3;
    }
    float2 tot = block_reduce_sum2(dot, rq);
    if (tid == 0) {
        float dmax = *dmaxf;
        float sqv = dmax * dmax / 127.0f;
        float t0 = 1.f / (1.f + expf(-theta[0]));
        float t1 = 1.f / (1.f + expf(-theta[1]));
        dinv2[row] = rsqrtf(t1 * sqv * sqv * tot.x + t0 * sqv * tot.y + 1.f);
    }
}

// ---------- K6: int8 GEMM; epilogue ranks v = p*dinv2_j per row, per-block top-4 ----------
// p = t1*s^2*(QQ^T) + t0*s*Q + I  (never materialized)
// LDS: staging (As+Bs, 16 KB) UNIONED with pbuf (33.3 KB) -- staging is dead
// after the K-loop; barrier before first pbuf write makes the overlay safe.
__global__ __launch_bounds__(256) void k_gemm(const i8_t* __restrict__ Sq,
                                              const i8_t* __restrict__ Tq,
                                              const float* __restrict__ dmaxf,
                                              const float* __restrict__ theta,
                                              const float* __restrict__ dinv2,
                                              float* __restrict__ candV,
                                              int* __restrict__ candJ) {
    __shared__ __align__(16) char smem[128 * 65 * 4];  // 33280 B
    i8_t* As = (i8_t*)smem;                    // [128*64] during K-loop
    i8_t* Bs = (i8_t*)(smem + 128 * 64);       // [128*64] during K-loop
    float (*pbuf)[65] = (float (*)[65])smem;   // [128][65] after K-loop
    int tid = threadIdx.x;
    int lane = tid & 63;
    int wave = tid >> 6;
    int wr = wave >> 1, wc = wave & 1;
    int bi = blockIdx.x, bj = blockIdx.y;

    // staging: thread t -> slot (row = t>>2 [+64], qslot = t&3); 16B chunks
    int qoff = ((tid & 3) ^ ((tid >> 3) & 3)) * 16;
    int row0 = tid >> 2;
    const i8_t* Ag0 = Sq + (size_t)(bi * 128 + row0) * N + qoff;
    const i8_t* Ag1 = Sq + (size_t)(bi * 128 + 64 + row0) * N + qoff;
    const i8_t* Bg0 = Tq + (size_t)(bj * 128 + row0) * N + qoff;
    const i8_t* Bg1 = Tq + (size_t)(bj * 128 + 64 + row0) * N + qoff;
    i8_t* Al0 = As + tid * 16;
    i8_t* Al1 = As + (tid + 256) * 16;
    i8_t* Bl0 = Bs + tid * 16;
    i8_t* Bl1 = Bs + (tid + 256) * 16;

    i32x4 acc[4][4];
    i32x4 z = {0, 0, 0, 0};
    #pragma unroll
    for (int i = 0; i < 4; i++)
        #pragma unroll
        for (int j = 0; j < 4; j++) acc[i][j] = z;

    int r = lane & 15, q = lane >> 4;
    int qs = q ^ ((r >> 1) & 3);  // fragment-read swizzle (2-way = free)
    int aoff = (wr * 64 + r) * 64 + qs * 16;
    int boff = (wc * 64 + r) * 64 + qs * 16;

    for (int k0 = 0; k0 < N; k0 += 64) {
        __syncthreads();
        gload16(Ag0 + k0, Al0);
        gload16(Ag1 + k0, Al1);
        gload16(Bg0 + k0, Bl0);
        gload16(Bg1 + k0, Bl1);
        __syncthreads();
        i32x4 af[4], bfr[4];
        #pragma unroll
        for (int mi = 0; mi < 4; mi++) af[mi] = *(const i32x4*)(As + aoff + mi * 16 * 64);
        #pragma unroll
        for (int ni = 0; ni < 4; ni++) bfr[ni] = *(const i32x4*)(Bs + boff + ni * 16 * 64);
        #pragma unroll
        for (int mi = 0; mi < 4; mi++)
            #pragma unroll
            for (int ni = 0; ni < 4; ni++)
                acc[mi][ni] = __builtin_amdgcn_mfma_i32_16x16x64_i8(af[mi], bfr[ni],
                                                                    acc[mi][ni], 0, 0, 0);
    }
    __syncthreads();  // staging LDS dead from here; pbuf overlay becomes safe

    // ---- epilogue: v = (t1s2*acc + t0s*Q + I) * dinv2_j, stored back into acc ----
    float dmax = *dmaxf;
    float sqv = dmax * dmax / 127.0f;
    float t0 = 1.f / (1.f + expf(-theta[0]));
    float t1 = 1.f / (1.f + expf(-theta[1]));
    float t0s = t0 * sqv;
    float t1s2 = t1 * sqv * sqv;
    int col = lane & 15, quad = lane >> 4;

    #pragma unroll
    for (int mi = 0; mi < 4; mi++) {
        int gi0 = bi * 128 + wr * 64 + mi * 16 + quad * 4;
        #pragma unroll
        for (int ni = 0; ni < 4; ni++) {
            int gj = bj * 128 + wc * 64 + ni * 16 + col;
            float djv = dinv2[gj];
            f32x4 pf;
            #pragma unroll
            for (int rr = 0; rr < 4; rr++) {
                int gi = gi0 + rr;
                float qv = (float)Sq[(size_t)gi * N + gj];  // t0 term from quantized S
                float p = t1s2 * (float)acc[mi][ni][rr] + t0s * qv + ((gi == gj) ? 1.f : 0.f);
                pf[rr] = p * djv;  // globally-comparable ranked value
            }
            acc[mi][ni] = __builtin_bit_cast(i32x4, pf);
        }
    }

    // ---- two-pass LDS round-trip + per-row top-4 scan ----
    float bv[4] = {-FLT_MAX, -FLT_MAX, -FLT_MAX, -FLT_MAX};
    int bjx[4] = {N, N, N, N};
    int srow = tid >> 1;        // scan row 0..127
    int shalf = tid & 1;        // which 32-col half this thread scans

    #pragma unroll
    for (int pass = 0; pass < 2; pass++) {
        if (wc == pass) {
            #pragma unroll
            for (int mi = 0; mi < 4; mi++) {
                int prow = wr * 64 + mi * 16 + quad * 4;
                #pragma unroll
                for (int ni = 0; ni < 4; ni++) {
                    f32x4 pf = __builtin_bit_cast(f32x4, acc[mi][ni]);
                    #pragma unroll
                    for (int rr = 0; rr < 4; rr++)
                        pbuf[prow + rr][ni * 16 + col] = pf[rr];
                }
            }
        }
        __syncthreads();
        int jbase = bj * 128 + pass * 64 + shalf * 32;
        for (int i = 0; i < 32; i++)
            ins4(pbuf[srow][shalf * 32 + i], jbase + i, bv, bjx);
        __syncthreads();
    }

    // merge partner (t^1 scanned the other 32-col halves), write 4 candidates/row
    float ov[4]; int oj[4];
    #pragma unroll
    for (int c = 0; c < 4; c++) { ov[c] = __shfl_xor(bv[c], 1); oj[c] = __shfl_xor(bjx[c], 1); }
    #pragma unroll
    for (int c = 0; c < 4; c++) ins4(ov[c], oj[c], bv, bjx);
    if (shalf == 0) {
        size_t base = ((size_t)(bi * 128 + srow) * 32 + bj) * 4;
        #pragma unroll
        for (int c = 0; c < 4; c++) { candV[base + c] = bv[c]; candJ[base + c] = bjx[c]; }
    }
}

// ---------- K7: per-row final top-4 (cands already scaled) + fused output ----------
// 128 candidates/row; 64 threads x 2 candidates each.
__global__ __launch_bounds__(64) void k_final(const float* __restrict__ candV,
                                              const int* __restrict__ candJ,
                                              const float* __restrict__ dinv2,
                                              const float* __restrict__ x,
                                              const float* __restrict__ W,
                                              const float* __restrict__ bvec,
                                              const int* __restrict__ kin,
                                              float* __restrict__ out) {
    int row = blockIdx.x, t = threadIdx.x;
    float2 cv = *(const float2*)(candV + (size_t)row * 128 + t * 2);
    int2 cj = *(const int2*)(candJ + (size_t)row * 128 + t * 2);
    float bv[4] = {-FLT_MAX, -FLT_MAX, -FLT_MAX, -FLT_MAX};
    int bj[4] = {N, N, N, N};
    ins4(cv.x, cj.x, bv, bj);
    ins4(cv.y, cj.y, bv, bj);
    // butterfly merge across 64 lanes (disjoint sets at every step)
    #pragma unroll
    for (int off = 1; off < 64; off <<= 1) {
        float ov[4]; int oj[4];
        #pragma unroll
        for (int c = 0; c < 4; c++) { ov[c] = __shfl_xor(bv[c], off); oj[c] = __shfl_xor(bj[c], off); }
        #pragma unroll
        for (int c = 0; c < 4; c++) ins4(ov[c], oj[c], bv, bj);
    }
    // all lanes hold the row's global top-4 (value = P_ij*dinv2_j, idx = j)
    int kk = kin[0];
    if (kk > 4) kk = 4;
    if (kk < 0) kk = 0;
    float sc = dinv2[row];
    float y = 0.f;
    for (int c = 0; c < kk; c++)
        y += sc * bv[c] * x[(size_t)bj[c] * DIN + t];
    __shared__ float ys[DIN];
    ys[t] = y;
    __syncthreads();
    const float4* w4 = (const float4*)(W + (size_t)t * DIN);
    const float4* y4 = (const float4*)ys;
    float o = bvec[t];
    #pragma unroll
    for (int d = 0; d < DIN / 4; d++) {
        float4 wv = w4[d], yv = y4[d];
        o += wv.x * yv.x + wv.y * yv.y + wv.z * yv.z + wv.w * yv.w;
    }
    out[(size_t)row * DIN + t] = o;
}

extern "C" void kernel_launch(void* const* d_in, const int* in_sizes, int n_in,
                              void* d_out, int out_size, void* d_ws, size_t ws_size,
                              hipStream_t stream) {
    const float* x = (const float*)d_in[0];
    const float* A = (const float*)d_in[1];
    const float* theta = (const float*)d_in[2];
    const float* W = (const float*)d_in[3];
    const float* b = (const float*)d_in[4];
    const int* kin = (const int*)d_in[5];
    float* out = (float*)d_out;

    // workspace layout (~36 MB)
    char* ws = (char*)d_ws;
    i8_t* Sq = (i8_t*)ws;                                  // 16 MB
    i8_t* Tq = (i8_t*)(ws + (size_t)N * N);                // 16 MB
    float* candV = (float*)(ws + (size_t)N * N * 2);       // 2 MB
    int* candJ = (int*)(ws + (size_t)N * N * 2 + (size_t)N * 128 * 4);  // 2 MB
    float* dinv = (float*)(ws + (size_t)N * N * 2 + (size_t)N * 128 * 8);
    float* dinv2 = dinv + N;
    float* colsumQ = dinv2 + N;
    float* dmaxf = colsumQ + N;

    k_rowsum_dinv<<<N, 256, 0, stream>>>(A, dinv);
    k_dmax<<<1, 1024, 0, stream>>>(dinv, dmaxf);
    k_make_sqt<<<dim3(64, 64), 256, 0, stream>>>(A, dinv, dmaxf, Sq, Tq);
    k_colsum<<<N, 256, 0, stream>>>(Tq, colsumQ);
    k_dinv2row<<<N, 256, 0, stream>>>(Sq, colsumQ, dmaxf, theta, dinv2);
    k_gemm<<<dim3(32, 32), 256, 0, stream>>>(Sq, Tq, dmaxf, theta, dinv2, candV, candJ);
    k_final<<<N, 64, 0, stream>>>(candV, candJ, dinv2, x, W, b, kin, out);
}